// Round 2
// baseline (1214.836 us; speedup 1.0000x reference)
//
#include <hip/hip_runtime.h>
#include <hip/hip_bf16.h>

typedef unsigned int u32;
typedef unsigned short u16;

__device__ __forceinline__ float bf2f(u32 u) {
  union { u32 i; float f; } v; v.i = u << 16; return v.f;
}
__device__ __forceinline__ float sigf(float x) {
  return 1.0f / (1.0f + __expf(-x));
}
__device__ __forceinline__ float tanhfast(float x) {
  return 2.0f / (1.0f + __expf(-2.0f * x)) - 1.0f;
}
__device__ __forceinline__ u16 f2bf(float f) {
  u32 u = __float_as_uint(f);
  u += 0x7fffu + ((u >> 16) & 1u);
  return (u16)(u >> 16);
}

// ---- runtime dtype detection: are the inputs bf16 or fp32? ----
// Read lstm1_Whh as u32 words. If data is bf16, each word's LOW u16 is a bf16
// of a ~N(0,0.08^2) weight -> its exponent bits (14:7) land in [100,140]
// essentially always. If data is fp32, the low u16 is uniform mantissa noise
// -> ~16% hit rate. Threshold at 60%.
__global__ void k_detect(const u32* __restrict__ w, int* __restrict__ flag) {
  __shared__ int cnt;
  if (threadIdx.x == 0) cnt = 0;
  __syncthreads();
  int c = 0;
  for (int i = threadIdx.x; i < 8192; i += 256) {
    const u32 lo = w[i] & 0xffffu;
    const u32 e = (lo >> 7) & 0xffu;
    c += (e >= 100u && e <= 140u) ? 1 : 0;
  }
  atomicAdd(&cnt, c);
  __syncthreads();
  if (threadIdx.x == 0) *flag = (cnt > 4915) ? 1 : 0;  // 60% of 8192
}

// ---- fused conversion of all small tensors to fp32 staging ----
struct Job { const void* s; float* d; int n; };
struct Jobs { Job j[26]; };

__global__ void k_cvt_all(Jobs J, const int* __restrict__ flag) {
  const Job jb = J.j[blockIdx.y];
  const int isbf = *flag;
  for (int i = blockIdx.x * 256 + threadIdx.x; i < jb.n; i += 32 * 256) {
    jb.d[i] = isbf ? bf2f(((const u16*)jb.s)[i]) : ((const float*)jb.s)[i];
  }
}

__global__ void k_init(const float* __restrict__ bias, float* __restrict__ C, int n, int mask) {
  int i = blockIdx.x * 256 + threadIdx.x;
  if (i < n) C[i] = bias[i & mask];
}

// C[M,N] (+)= A[M,K] @ W[N,K]^T (+bias). A fp32 (optional tanh on load).
// W dtype: fp32 if (!wfollow || *dflag==0 ... ) -- wfollow selects whether W
// follows the detected input dtype (raw d_in weight) or is pre-staged fp32.
// grid: (M/64, N/64, splitK). atomic path requires C pre-initialized w/ bias.
__launch_bounds__(256)
__global__ void k_gemm(const float* __restrict__ A, int lda,
                       const void* __restrict__ Wv, int ldw,
                       const float* __restrict__ bias,
                       float* __restrict__ C, int ldc,
                       int K, int actA, int atom, int wfollow,
                       const int* __restrict__ dflag)
{
  __shared__ float As[16][65];
  __shared__ float Ws[16][65];
  const int isbf = wfollow ? *dflag : 0;
  const int tid = threadIdx.x;
  const int tx = tid & 15, ty = tid >> 4;
  const int m0 = blockIdx.x * 64, n0 = blockIdx.y * 64;
  const int kc = K / gridDim.z;
  const int k0 = blockIdx.z * kc;
  const int lr = tid >> 2;          // 0..63
  const int lk = (tid & 3) << 2;    // 0,4,8,12
  float acc[4][4] = {{0.f}};
  const float* Ap   = A + (size_t)(m0 + lr) * lda + k0 + lk;
  const u16*   Wp16 = (const u16*)Wv   + (size_t)(n0 + lr) * ldw + k0 + lk;
  const float* Wp32 = (const float*)Wv + (size_t)(n0 + lr) * ldw + k0 + lk;
  for (int kk = 0; kk < kc; kk += 16) {
    float4 av = *(const float4*)(Ap + kk);
    float w0, w1, w2, w3;
    if (isbf) {
      ushort4 wv = *(const ushort4*)(Wp16 + kk);
      w0 = bf2f(wv.x); w1 = bf2f(wv.y); w2 = bf2f(wv.z); w3 = bf2f(wv.w);
    } else {
      float4 wv = *(const float4*)(Wp32 + kk);
      w0 = wv.x; w1 = wv.y; w2 = wv.z; w3 = wv.w;
    }
    if (actA) {
      av.x = tanhfast(av.x); av.y = tanhfast(av.y);
      av.z = tanhfast(av.z); av.w = tanhfast(av.w);
    }
    __syncthreads();
    As[lk+0][lr] = av.x; As[lk+1][lr] = av.y;
    As[lk+2][lr] = av.z; As[lk+3][lr] = av.w;
    Ws[lk+0][lr] = w0; Ws[lk+1][lr] = w1;
    Ws[lk+2][lr] = w2; Ws[lk+3][lr] = w3;
    __syncthreads();
    #pragma unroll
    for (int k = 0; k < 16; ++k) {
      float a[4], w[4];
      #pragma unroll
      for (int i = 0; i < 4; ++i) a[i] = As[k][ty + 16*i];
      #pragma unroll
      for (int j = 0; j < 4; ++j) w[j] = Ws[k][tx + 16*j];
      #pragma unroll
      for (int i = 0; i < 4; ++i)
        #pragma unroll
        for (int j = 0; j < 4; ++j)
          acc[i][j] = fmaf(a[i], w[j], acc[i][j]);
    }
  }
  #pragma unroll
  for (int i = 0; i < 4; ++i) {
    const int m = m0 + ty + 16*i;
    #pragma unroll
    for (int j = 0; j < 4; ++j) {
      const int n = n0 + tx + 16*j;
      if (atom) atomicAdd(&C[(size_t)m*ldc + n], acc[i][j]);
      else {
        const float bv = bias ? bias[n] : 0.0f;
        C[(size_t)m*ldc + n] = acc[i][j] + bv;
      }
    }
  }
}

// One block per (batch element, direction). 512 threads: thread j owns gate row
// j of Whh (fp32 staged, in registers). Zin = precomputed x@Wih.T + b.
__launch_bounds__(512)
__global__ void k_rec(const float* __restrict__ Zf, const float* __restrict__ Zb,
                      const float* __restrict__ Wf, const float* __restrict__ Wb,
                      float* __restrict__ HS, int hstride, int offF, int offB,
                      float* __restrict__ Cout)
{
  const int b = blockIdx.x & 63;
  const int dir = blockIdx.x >> 6;
  const float* Z = dir ? Zb : Zf;
  const float* Wg = dir ? Wb : Wf;
  const int off = dir ? offB : offF;
  const int tid = threadIdx.x;

  __shared__ __align__(16) float hlds[128];
  __shared__ float zlds[512];

  float w[128];
  {
    const float4* wr = (const float4*)(Wg + (size_t)tid * 128);
    #pragma unroll
    for (int q = 0; q < 32; ++q) {
      const float4 u = wr[q];
      w[q*4+0] = u.x; w[q*4+1] = u.y; w[q*4+2] = u.z; w[q*4+3] = u.w;
    }
  }
  float creg = 0.0f;
  if (tid < 128) hlds[tid] = 0.0f;
  __syncthreads();

  for (int t = 0; t < 64; ++t) {
    const int s = dir ? (63 - t) : t;
    float acc = Z[((size_t)s*64 + b)*512 + tid];
    #pragma unroll
    for (int k4 = 0; k4 < 32; ++k4) {
      const float4 h4 = ((const float4*)hlds)[k4];
      acc = fmaf(w[k4*4+0], h4.x, acc);
      acc = fmaf(w[k4*4+1], h4.y, acc);
      acc = fmaf(w[k4*4+2], h4.z, acc);
      acc = fmaf(w[k4*4+3], h4.w, acc);
    }
    zlds[tid] = acc;
    __syncthreads();
    if (tid < 128) {
      const float zi = zlds[tid], zf = zlds[tid+128], zg = zlds[tid+256], zo = zlds[tid+384];
      const float cc = sigf(zf) * creg + sigf(zi) * tanhfast(zg);
      const float hh = sigf(zo) * tanhfast(cc);
      creg = cc;
      hlds[tid] = hh;
      HS[((size_t)s*64 + b)*hstride + off + tid] = hh;
    }
    __syncthreads();
  }
  if (Cout != nullptr && tid < 128) Cout[b*128 + tid] = creg;
}

// Decoder: one block per element, 64 steps. xin_t == h_{t-1}, so cell uses
// Wsum = Wih + Whh (fp32 registers). Attention uses hoisted enc_proj.
__launch_bounds__(512)
__global__ void k_dec(const float* __restrict__ enco, const float* __restrict__ encp,
                      const float* __restrict__ ec,
                      const float* __restrict__ Wih, const float* __restrict__ Whh,
                      const float* __restrict__ db, const float* __restrict__ attW,
                      const float* __restrict__ attw, float* __restrict__ flat)
{
  const int b = blockIdx.x;
  const int tid = threadIdx.x;
  __shared__ __align__(16) float hlds[128];
  __shared__ float zlds[512];
  __shared__ __align__(16) float enc_b[64*128];  // 32 KB fp32
  __shared__ u16 ep_b[64*128];                   // 16 KB bf16 (scores only)
  __shared__ float hproj[128];
  __shared__ float scores[64];
  __shared__ float awlds[64];
  __shared__ float attw_l[128];

  for (int i = tid; i < 64*128; i += 512) {
    const int s = i >> 7, k = i & 127;
    const size_t g = ((size_t)s*64 + b)*128 + k;
    enc_b[i] = enco[g];
    ep_b[i] = f2bf(encp[g]);
  }

  float w[128];
  {
    const float4* wi4 = (const float4*)(Wih + (size_t)tid*128);
    const float4* wh4 = (const float4*)(Whh + (size_t)tid*128);
    #pragma unroll
    for (int q = 0; q < 32; ++q) {
      const float4 a = wi4[q], c = wh4[q];
      w[q*4+0] = a.x + c.x; w[q*4+1] = a.y + c.y;
      w[q*4+2] = a.z + c.z; w[q*4+3] = a.w + c.w;
    }
  }
  const float bj = db[tid];
  float creg = 0.0f;
  if (tid < 128) {
    hlds[tid] = enco[((size_t)63*64 + b)*128 + tid];
    creg = ec[b*128 + tid];
    attw_l[tid] = attw[tid];
  }
  __syncthreads();

  for (int t = 0; t < 64; ++t) {
    // cell pre-activation z[tid]
    float acc = bj;
    #pragma unroll
    for (int k4 = 0; k4 < 32; ++k4) {
      const float4 h4 = ((const float4*)hlds)[k4];
      acc = fmaf(w[k4*4+0], h4.x, acc);
      acc = fmaf(w[k4*4+1], h4.y, acc);
      acc = fmaf(w[k4*4+2], h4.z, acc);
      acc = fmaf(w[k4*4+3], h4.w, acc);
    }
    zlds[tid] = acc;
    __syncthreads();
    // gates -> h', c'
    if (tid < 128) {
      const float zi = zlds[tid], zf2 = zlds[tid+128], zg = zlds[tid+256], zo = zlds[tid+384];
      const float cc = sigf(zf2) * creg + sigf(zi) * tanhfast(zg);
      const float hh = sigf(zo) * tanhfast(cc);
      creg = cc;
      hlds[tid] = hh;
      flat[(size_t)b*16384 + t*256 + tid] = hh;
    }
    __syncthreads();
    // h_proj = att_fc_W @ h'
    if (tid < 128) {
      const float4* ar = (const float4*)(attW + (size_t)tid*128);
      float hp = 0.0f;
      #pragma unroll
      for (int q = 0; q < 32; ++q) {
        const float4 a = ar[q];
        const float4 h4 = ((const float4*)hlds)[q];
        hp = fmaf(a.x, h4.x, hp);
        hp = fmaf(a.y, h4.y, hp);
        hp = fmaf(a.z, h4.z, hp);
        hp = fmaf(a.w, h4.w, hp);
      }
      hproj[tid] = hp;
    }
    __syncthreads();
    // scores[s] = att_w . tanh(hproj + enc_proj[s]) ; 8 threads per s
    {
      const int s = tid >> 3;
      const int kk0 = (tid & 7) * 16;
      float pacc = 0.0f;
      #pragma unroll
      for (int k = 0; k < 16; ++k) {
        const int k2 = kk0 + k;
        pacc = fmaf(attw_l[k2], tanhfast(hproj[k2] + bf2f(ep_b[s*128 + k2])), pacc);
      }
      pacc += __shfl_down(pacc, 4, 8);
      pacc += __shfl_down(pacc, 2, 8);
      pacc += __shfl_down(pacc, 1, 8);
      if ((tid & 7) == 0) scores[s] = pacc;
    }
    __syncthreads();
    // softmax over S (wave 0)
    if (tid < 64) {
      const float x = scores[tid];
      float m = x;
      #pragma unroll
      for (int d2 = 32; d2 >= 1; d2 >>= 1) m = fmaxf(m, __shfl_xor(m, d2, 64));
      const float e = __expf(x - m);
      float ssum = e;
      #pragma unroll
      for (int d2 = 32; d2 >= 1; d2 >>= 1) ssum += __shfl_xor(ssum, d2, 64);
      awlds[tid] = e / ssum;
    }
    __syncthreads();
    // ctx = sum_s aw[s] * enc_out[s]
    if (tid < 128) {
      float cx = 0.0f;
      #pragma unroll 8
      for (int s2 = 0; s2 < 64; ++s2)
        cx = fmaf(awlds[s2], enc_b[s2*128 + tid], cx);
      flat[(size_t)b*16384 + t*256 + 128 + tid] = cx;
    }
    __syncthreads();
  }
}

__global__ void k_head(const float* __restrict__ a4, const float* __restrict__ outW,
                       const float* __restrict__ outb, void* __restrict__ out,
                       const int* __restrict__ dflag)
{
  const int b = threadIdx.x;  // 64 threads
  float acc = outb[0];
  #pragma unroll 8
  for (int k = 0; k < 128; ++k)
    acc = fmaf(outW[k], tanhfast(a4[b*128 + k]), acc);
  if (*dflag) ((u16*)out)[b] = f2bf(acc);
  else        ((float*)out)[b] = acc;
}

extern "C" void kernel_launch(void* const* d_in, const int* in_sizes, int n_in,
                              void* d_out, int out_size, void* d_ws, size_t ws_size,
                              hipStream_t stream)
{
  (void)in_sizes; (void)n_in; (void)out_size; (void)ws_size;

  float* p = (float*)d_ws;
  int*   flagp = (int*)p;    p += 64;
  float* x0    = p; p += 64*64*64;
  // fp32-staged weights/biases
  float* cl1Wih = p; p += 512*64;
  float* cl1Whh = p; p += 512*128;
  float* cl1b   = p; p += 512;
  float* c2fWih = p; p += 512*128;
  float* c2fWhh = p; p += 512*128;
  float* c2fb   = p; p += 512;
  float* c2bWih = p; p += 512*128;
  float* c2bWhh = p; p += 512*128;
  float* c2bb   = p; p += 512;
  float* c3fWih = p; p += 512*256;
  float* c3fWhh = p; p += 512*128;
  float* c3fb   = p; p += 512;
  float* c3bWih = p; p += 512*256;
  float* c3bWhh = p; p += 512*128;
  float* c3bb   = p; p += 512;
  float* ceWih  = p; p += 512*256;
  float* ceWhh  = p; p += 512*128;
  float* ceb    = p; p += 512;
  float* cdWih  = p; p += 512*128;
  float* cdWhh  = p; p += 512*128;
  float* cdb    = p; p += 512;
  float* cattW  = p; p += 128*128;
  float* cattw  = p; p += 128;
  float* cW1b   = p; p += 1024;
  float* cW2b   = p; p += 512;
  float* cW3b   = p; p += 256;
  float* cW4b   = p; p += 128;
  float* coW    = p; p += 128;
  float* cob    = p; p += 16;
  // activations
  float* Zf   = p; p += 4096*512;
  float* Zb   = p; p += 4096*512;
  float* h1   = p; p += 4096*128;
  float* x2   = p; p += 4096*256;
  float* x3   = p; p += 4096*256;
  float* enco = p; p += 4096*128;
  float* encp = p; p += 4096*128;
  float* ec   = p; p += 64*128;
  float* flat = p; p += 64*16384;
  float* a1   = p; p += 64*1024;
  float* a2   = p; p += 64*512;
  float* a3   = p; p += 64*256;
  float* a4   = p; p += 64*128;

  k_detect<<<1, 256, 0, stream>>>((const u32*)d_in[2], flagp);

  Jobs J;
  int nj = 0;
  auto add = [&](const void* s, float* d, int n) { J.j[nj].s = s; J.j[nj].d = d; J.j[nj].n = n; ++nj; };
  add(d_in[0],  x0,     64*64*64);
  add(d_in[1],  cl1Wih, 512*64);
  add(d_in[2],  cl1Whh, 512*128);
  add(d_in[3],  cl1b,   512);
  add(d_in[4],  c2fWih, 512*128);
  add(d_in[5],  c2fWhh, 512*128);
  add(d_in[6],  c2fb,   512);
  add(d_in[7],  c2bWih, 512*128);
  add(d_in[8],  c2bWhh, 512*128);
  add(d_in[9],  c2bb,   512);
  add(d_in[10], c3fWih, 512*256);
  add(d_in[11], c3fWhh, 512*128);
  add(d_in[12], c3fb,   512);
  add(d_in[13], c3bWih, 512*256);
  add(d_in[14], c3bWhh, 512*128);
  add(d_in[15], c3bb,   512);
  add(d_in[16], ceWih,  512*256);
  add(d_in[17], ceWhh,  512*128);
  add(d_in[18], ceb,    512);
  add(d_in[19], cdWih,  512*128);
  add(d_in[20], cdWhh,  512*128);
  add(d_in[21], cdb,    512);
  add(d_in[22], cattW,  128*128);
  add(d_in[23], cattw,  128);
  add(d_in[25], cW1b,   1024);
  add(d_in[27], cW2b,   512);
  // reuse last slots via a second batch below (26-job struct capacity)
  k_cvt_all<<<dim3(32, nj), 256, 0, stream>>>(J, flagp);

  Jobs J2;
  int nj2 = 0;
  auto add2 = [&](const void* s, float* d, int n) { J2.j[nj2].s = s; J2.j[nj2].d = d; J2.j[nj2].n = n; ++nj2; };
  add2(d_in[29], cW3b, 256);
  add2(d_in[31], cW4b, 128);
  add2(d_in[32], coW,  128);
  add2(d_in[33], cob,  1);
  k_cvt_all<<<dim3(4, nj2), 256, 0, stream>>>(J2, flagp);

  // lstm1
  k_gemm<<<dim3(64,8,1), 256, 0, stream>>>(x0, 64, cl1Wih, 64, cl1b, Zf, 512, 64, 0, 0, 0, flagp);
  k_rec<<<64, 512, 0, stream>>>(Zf, Zf, cl1Whh, cl1Whh, h1, 128, 0, 0, nullptr);

  // biLSTM 2
  k_gemm<<<dim3(64,8,1), 256, 0, stream>>>(h1, 128, c2fWih, 128, c2fb, Zf, 512, 128, 0, 0, 0, flagp);
  k_gemm<<<dim3(64,8,1), 256, 0, stream>>>(h1, 128, c2bWih, 128, c2bb, Zb, 512, 128, 0, 0, 0, flagp);
  k_rec<<<128, 512, 0, stream>>>(Zf, Zb, c2fWhh, c2bWhh, x2, 256, 0, 128, nullptr);

  // biLSTM 3
  k_gemm<<<dim3(64,8,1), 256, 0, stream>>>(x2, 256, c3fWih, 256, c3fb, Zf, 512, 256, 0, 0, 0, flagp);
  k_gemm<<<dim3(64,8,1), 256, 0, stream>>>(x2, 256, c3bWih, 256, c3bb, Zb, 512, 256, 0, 0, 0, flagp);
  k_rec<<<128, 512, 0, stream>>>(Zf, Zb, c3fWhh, c3bWhh, x3, 256, 0, 128, nullptr);

  // encoder
  k_gemm<<<dim3(64,8,1), 256, 0, stream>>>(x3, 256, ceWih, 256, ceb, Zf, 512, 256, 0, 0, 0, flagp);
  k_rec<<<64, 512, 0, stream>>>(Zf, Zf, ceWhh, ceWhh, enco, 128, 0, 0, ec);

  // hoisted attention projection of enc_out
  k_gemm<<<dim3(64,2,1), 256, 0, stream>>>(enco, 128, cattW, 128, nullptr, encp, 128, 128, 0, 0, 0, flagp);

  // decoder + attention -> flat [64, 16384]
  k_dec<<<64, 512, 0, stream>>>(enco, encp, ec, cdWih, cdWhh, cdb, cattW, cattw, flat);

  // MLP (fp32 accum; split-K with bias pre-init + atomics; tanh fused into A-load)
  k_init<<<(64*1024+255)/256, 256, 0, stream>>>(cW1b, a1, 64*1024, 1023);
  k_gemm<<<dim3(1,16,16), 256, 0, stream>>>(flat, 16384, d_in[24], 16384, nullptr, a1, 1024, 16384, 0, 1, 1, flagp);
  k_init<<<(64*512+255)/256, 256, 0, stream>>>(cW2b, a2, 64*512, 511);
  k_gemm<<<dim3(1,8,4), 256, 0, stream>>>(a1, 1024, d_in[26], 1024, nullptr, a2, 512, 1024, 1, 1, 1, flagp);
  k_init<<<(64*256+255)/256, 256, 0, stream>>>(cW3b, a3, 64*256, 255);
  k_gemm<<<dim3(1,4,4), 256, 0, stream>>>(a2, 512, d_in[28], 512, nullptr, a3, 256, 512, 1, 1, 1, flagp);
  k_init<<<(64*128+255)/256, 256, 0, stream>>>(cW4b, a4, 64*128, 127);
  k_gemm<<<dim3(1,2,2), 256, 0, stream>>>(a3, 256, d_in[30], 256, nullptr, a4, 128, 256, 1, 1, 1, flagp);

  k_head<<<1, 64, 0, stream>>>(a4, coW, cob, d_out, flagp);
}

// Round 3
// 999.798 us; speedup vs baseline: 1.2151x; 1.2151x over previous
//
#include <hip/hip_runtime.h>
#include <hip/hip_bf16.h>

typedef unsigned int u32;
typedef unsigned short u16;

__device__ __forceinline__ float bf2f(u32 u) {
  union { u32 i; float f; } v; v.i = u << 16; return v.f;
}
__device__ __forceinline__ float sigf(float x) {
  return 1.0f / (1.0f + __expf(-x));
}
__device__ __forceinline__ float tanhfast(float x) {
  return 2.0f / (1.0f + __expf(-2.0f * x)) - 1.0f;
}
__device__ __forceinline__ u16 f2bf(float f) {
  u32 u = __float_as_uint(f);
  u += 0x7fffu + ((u >> 16) & 1u);
  return (u16)(u >> 16);
}

// ---- runtime dtype detection (bf16 vs fp32 inputs) ----
__global__ void k_detect(const u32* __restrict__ w, int* __restrict__ flag) {
  __shared__ int cnt;
  if (threadIdx.x == 0) cnt = 0;
  __syncthreads();
  int c = 0;
  for (int i = threadIdx.x; i < 8192; i += 256) {
    const u32 lo = w[i] & 0xffffu;
    const u32 e = (lo >> 7) & 0xffu;
    c += (e >= 100u && e <= 140u) ? 1 : 0;
  }
  atomicAdd(&cnt, c);
  __syncthreads();
  if (threadIdx.x == 0) *flag = (cnt > 4915) ? 1 : 0;
}

struct Job { const void* s; float* d; int n; };
struct Jobs { Job j[26]; };

__global__ void k_cvt_all(Jobs J, const int* __restrict__ flag) {
  const Job jb = J.j[blockIdx.y];
  const int isbf = *flag;
  for (int i = blockIdx.x * 256 + threadIdx.x; i < jb.n; i += 32 * 256) {
    jb.d[i] = isbf ? bf2f(((const u16*)jb.s)[i]) : ((const float*)jb.s)[i];
  }
}

__global__ void k_init(const float* __restrict__ bias, float* __restrict__ C, int n, int mask) {
  int i = blockIdx.x * 256 + threadIdx.x;
  if (i < n) C[i] = bias[i & mask];
}

// C[M,N] (+)= A[M,K] @ W[N,K]^T (+bias). Unchanged from round 2 (passed).
__launch_bounds__(256)
__global__ void k_gemm(const float* __restrict__ A, int lda,
                       const void* __restrict__ Wv, int ldw,
                       const float* __restrict__ bias,
                       float* __restrict__ C, int ldc,
                       int K, int actA, int atom, int wfollow,
                       const int* __restrict__ dflag)
{
  __shared__ float As[16][65];
  __shared__ float Ws[16][65];
  const int isbf = wfollow ? *dflag : 0;
  const int tid = threadIdx.x;
  const int tx = tid & 15, ty = tid >> 4;
  const int m0 = blockIdx.x * 64, n0 = blockIdx.y * 64;
  const int kc = K / gridDim.z;
  const int k0 = blockIdx.z * kc;
  const int lr = tid >> 2;
  const int lk = (tid & 3) << 2;
  float acc[4][4] = {{0.f}};
  const float* Ap   = A + (size_t)(m0 + lr) * lda + k0 + lk;
  const u16*   Wp16 = (const u16*)Wv   + (size_t)(n0 + lr) * ldw + k0 + lk;
  const float* Wp32 = (const float*)Wv + (size_t)(n0 + lr) * ldw + k0 + lk;
  for (int kk = 0; kk < kc; kk += 16) {
    float4 av = *(const float4*)(Ap + kk);
    float w0, w1, w2, w3;
    if (isbf) {
      ushort4 wv = *(const ushort4*)(Wp16 + kk);
      w0 = bf2f(wv.x); w1 = bf2f(wv.y); w2 = bf2f(wv.z); w3 = bf2f(wv.w);
    } else {
      float4 wv = *(const float4*)(Wp32 + kk);
      w0 = wv.x; w1 = wv.y; w2 = wv.z; w3 = wv.w;
    }
    if (actA) {
      av.x = tanhfast(av.x); av.y = tanhfast(av.y);
      av.z = tanhfast(av.z); av.w = tanhfast(av.w);
    }
    __syncthreads();
    As[lk+0][lr] = av.x; As[lk+1][lr] = av.y;
    As[lk+2][lr] = av.z; As[lk+3][lr] = av.w;
    Ws[lk+0][lr] = w0; Ws[lk+1][lr] = w1;
    Ws[lk+2][lr] = w2; Ws[lk+3][lr] = w3;
    __syncthreads();
    #pragma unroll
    for (int k = 0; k < 16; ++k) {
      float a[4], w[4];
      #pragma unroll
      for (int i = 0; i < 4; ++i) a[i] = As[k][ty + 16*i];
      #pragma unroll
      for (int j = 0; j < 4; ++j) w[j] = Ws[k][tx + 16*j];
      #pragma unroll
      for (int i = 0; i < 4; ++i)
        #pragma unroll
        for (int j = 0; j < 4; ++j)
          acc[i][j] = fmaf(a[i], w[j], acc[i][j]);
    }
  }
  #pragma unroll
  for (int i = 0; i < 4; ++i) {
    const int m = m0 + ty + 16*i;
    #pragma unroll
    for (int j = 0; j < 4; ++j) {
      const int n = n0 + tx + 16*j;
      if (atom) atomicAdd(&C[(size_t)m*ldc + n], acc[i][j]);
      else {
        const float bv = bias ? bias[n] : 0.0f;
        C[(size_t)m*ldc + n] = acc[i][j] + bv;
      }
    }
  }
}

// Recurrence: thread (r=tid>>2, kq=tid&3) owns rows {r+128j} x k-chunk kq.
// w in 128 VGPRs (launch_bounds(512,1) -> 256 budget, no spills).
// h chunks in LDS at stride 40 floats (disjoint banks per instruction).
__launch_bounds__(512, 1)
__global__ void k_rec(const float* __restrict__ Zf, const float* __restrict__ Zb,
                      const float* __restrict__ Wf, const float* __restrict__ Wb,
                      float* __restrict__ HS, int hstride, int offF, int offB,
                      float* __restrict__ Cout)
{
  const int b = blockIdx.x & 63;
  const int dir = blockIdx.x >> 6;
  const float* Z = dir ? Zb : Zf;
  const float* Wg = dir ? Wb : Wf;
  const int off = dir ? offB : offF;
  const int tid = threadIdx.x;
  const int r = tid >> 2, kq = tid & 3;

  __shared__ __align__(16) float hch[4*40];
  __shared__ float zlds[512];

  float w[4][32];
  #pragma unroll
  for (int j = 0; j < 4; ++j) {
    const float* wr = Wg + (size_t)(r + 128*j) * 128 + kq*32;
    #pragma unroll
    for (int q = 0; q < 8; ++q) {
      const float4 u = *(const float4*)(wr + q*4);
      w[j][q*4+0]=u.x; w[j][q*4+1]=u.y; w[j][q*4+2]=u.z; w[j][q*4+3]=u.w;
    }
  }
  float creg = 0.0f;
  if (tid < 128) hch[(tid>>5)*40 + (tid&31)] = 0.0f;

  float zc[4];
  {
    const float* zp = Z + ((size_t)(dir ? 63 : 0)*64 + b)*512;
    #pragma unroll
    for (int j = 0; j < 4; ++j) zc[j] = zp[r + 128*j];
  }
  __syncthreads();

  for (int t = 0; t < 64; ++t) {
    const int s = dir ? (63 - t) : t;
    float zn[4] = {0.f,0.f,0.f,0.f};
    if (t < 63) {
      const int s2 = dir ? (62 - t) : (t + 1);
      const float* zp = Z + ((size_t)s2*64 + b)*512;
      #pragma unroll
      for (int j = 0; j < 4; ++j) zn[j] = zp[r + 128*j];
    }
    float a[4] = {0.f,0.f,0.f,0.f};
    #pragma unroll
    for (int q = 0; q < 8; ++q) {
      const float4 h4 = *(const float4*)&hch[kq*40 + q*4];
      #pragma unroll
      for (int j = 0; j < 4; ++j) {
        a[j] = fmaf(w[j][q*4+0], h4.x, a[j]);
        a[j] = fmaf(w[j][q*4+1], h4.y, a[j]);
        a[j] = fmaf(w[j][q*4+2], h4.z, a[j]);
        a[j] = fmaf(w[j][q*4+3], h4.w, a[j]);
      }
    }
    #pragma unroll
    for (int j = 0; j < 4; ++j) {
      a[j] += __shfl_xor(a[j], 1, 64);
      a[j] += __shfl_xor(a[j], 2, 64);
    }
    zlds[r + 128*kq] = a[kq] + zc[kq];
    __syncthreads();
    if (tid < 128) {
      const float zi = zlds[tid], zf = zlds[tid+128], zg = zlds[tid+256], zo = zlds[tid+384];
      const float cc = sigf(zf) * creg + sigf(zi) * tanhfast(zg);
      const float hh = sigf(zo) * tanhfast(cc);
      creg = cc;
      hch[(tid>>5)*40 + (tid&31)] = hh;
      HS[((size_t)s*64 + b)*hstride + off + tid] = hh;
    }
    __syncthreads();
    #pragma unroll
    for (int j = 0; j < 4; ++j) zc[j] = zn[j];
  }
  if (Cout != nullptr && tid < 128) Cout[b*128 + tid] = creg;
}

// Decoder: 4-way-split cell (Wsum = Wih+Whh since xin == h_prev),
// hproj/scores/ctx parallelized across all 512 threads. 5 barriers/step.
#define EPS 136   // ep_b row stride (u16)
#define ENS 129   // enc_b row stride (f32)
__launch_bounds__(512, 1)
__global__ void k_dec(const float* __restrict__ enco, const float* __restrict__ encp,
                      const float* __restrict__ ec,
                      const float* __restrict__ Wih, const float* __restrict__ Whh,
                      const float* __restrict__ db, const float* __restrict__ attW,
                      const float* __restrict__ attw, float* __restrict__ flat)
{
  const int b = blockIdx.x;
  const int tid = threadIdx.x;
  const int r = tid >> 2, kq = tid & 3;
  const int sidx = tid >> 3, ko8 = tid & 7;

  __shared__ __align__(16) float hch[4*40];
  __shared__ float zlds[512];
  __shared__ float enc_b[64*ENS];
  __shared__ __align__(16) u16 ep_b[64*EPS];
  __shared__ __align__(16) float hproj[128];
  __shared__ float scores[64];
  __shared__ float awlds[64];

  for (int i = tid; i < 64*128; i += 512) {
    const int s = i >> 7, k = i & 127;
    const size_t g = ((size_t)s*64 + b)*128 + k;
    enc_b[s*ENS + k] = enco[g];
    ep_b[s*EPS + k] = f2bf(encp[g]);
  }

  float w[4][32];
  #pragma unroll
  for (int j = 0; j < 4; ++j) {
    const float* wi = Wih + (size_t)(r + 128*j)*128 + kq*32;
    const float* wh = Whh + (size_t)(r + 128*j)*128 + kq*32;
    #pragma unroll
    for (int q = 0; q < 8; ++q) {
      const float4 a4 = *(const float4*)(wi + q*4);
      const float4 c4 = *(const float4*)(wh + q*4);
      w[j][q*4+0]=a4.x+c4.x; w[j][q*4+1]=a4.y+c4.y;
      w[j][q*4+2]=a4.z+c4.z; w[j][q*4+3]=a4.w+c4.w;
    }
  }
  float att_r[32];
  {
    const float* ar = attW + (size_t)r*128 + kq*32;
    #pragma unroll
    for (int q = 0; q < 8; ++q) {
      const float4 a4 = *(const float4*)(ar + q*4);
      att_r[q*4+0]=a4.x; att_r[q*4+1]=a4.y; att_r[q*4+2]=a4.z; att_r[q*4+3]=a4.w;
    }
  }
  float aw_r[16];
  #pragma unroll
  for (int k = 0; k < 16; ++k) aw_r[k] = attw[ko8*16 + k];

  const float bq = db[r + 128*kq];
  float creg = 0.0f;
  if (tid < 128) {
    hch[(tid>>5)*40 + (tid&31)] = enco[((size_t)63*64 + b)*128 + tid];
    creg = ec[b*128 + tid];
  }
  __syncthreads();

  for (int t = 0; t < 64; ++t) {
    // --- cell ---
    float a[4] = {0.f,0.f,0.f,0.f};
    #pragma unroll
    for (int q = 0; q < 8; ++q) {
      const float4 h4 = *(const float4*)&hch[kq*40 + q*4];
      #pragma unroll
      for (int j = 0; j < 4; ++j) {
        a[j] = fmaf(w[j][q*4+0], h4.x, a[j]);
        a[j] = fmaf(w[j][q*4+1], h4.y, a[j]);
        a[j] = fmaf(w[j][q*4+2], h4.z, a[j]);
        a[j] = fmaf(w[j][q*4+3], h4.w, a[j]);
      }
    }
    #pragma unroll
    for (int j = 0; j < 4; ++j) {
      a[j] += __shfl_xor(a[j], 1, 64);
      a[j] += __shfl_xor(a[j], 2, 64);
    }
    zlds[r + 128*kq] = a[kq] + bq;
    __syncthreads();
    // --- gates ---
    if (tid < 128) {
      const float zi = zlds[tid], zf2 = zlds[tid+128], zg = zlds[tid+256], zo = zlds[tid+384];
      const float cc = sigf(zf2) * creg + sigf(zi) * tanhfast(zg);
      const float hh = sigf(zo) * tanhfast(cc);
      creg = cc;
      hch[(tid>>5)*40 + (tid&31)] = hh;
      flat[(size_t)b*16384 + t*256 + tid] = hh;
    }
    __syncthreads();
    // --- hproj (4-way split) ---
    {
      float hp = 0.0f;
      #pragma unroll
      for (int q = 0; q < 8; ++q) {
        const float4 h4 = *(const float4*)&hch[kq*40 + q*4];
        hp = fmaf(att_r[q*4+0], h4.x, hp);
        hp = fmaf(att_r[q*4+1], h4.y, hp);
        hp = fmaf(att_r[q*4+2], h4.z, hp);
        hp = fmaf(att_r[q*4+3], h4.w, hp);
      }
      hp += __shfl_xor(hp, 1, 64);
      hp += __shfl_xor(hp, 2, 64);
      if (kq == 0) hproj[r] = hp;
    }
    __syncthreads();
    // --- scores (8 threads per s, vector bf16 reads) ---
    {
      const uint4 e0 = *(const uint4*)&ep_b[sidx*EPS + ko8*16];
      const uint4 e1 = *(const uint4*)&ep_b[sidx*EPS + ko8*16 + 8];
      const float4 hpa = *(const float4*)&hproj[ko8*16];
      const float4 hpb = *(const float4*)&hproj[ko8*16 + 4];
      const float4 hpc = *(const float4*)&hproj[ko8*16 + 8];
      const float4 hpd = *(const float4*)&hproj[ko8*16 + 12];
      float pacc = 0.0f;
      pacc = fmaf(aw_r[0],  tanhfast(hpa.x + bf2f(e0.x & 0xffffu)), pacc);
      pacc = fmaf(aw_r[1],  tanhfast(hpa.y + bf2f(e0.x >> 16)), pacc);
      pacc = fmaf(aw_r[2],  tanhfast(hpa.z + bf2f(e0.y & 0xffffu)), pacc);
      pacc = fmaf(aw_r[3],  tanhfast(hpa.w + bf2f(e0.y >> 16)), pacc);
      pacc = fmaf(aw_r[4],  tanhfast(hpb.x + bf2f(e0.z & 0xffffu)), pacc);
      pacc = fmaf(aw_r[5],  tanhfast(hpb.y + bf2f(e0.z >> 16)), pacc);
      pacc = fmaf(aw_r[6],  tanhfast(hpb.z + bf2f(e0.w & 0xffffu)), pacc);
      pacc = fmaf(aw_r[7],  tanhfast(hpb.w + bf2f(e0.w >> 16)), pacc);
      pacc = fmaf(aw_r[8],  tanhfast(hpc.x + bf2f(e1.x & 0xffffu)), pacc);
      pacc = fmaf(aw_r[9],  tanhfast(hpc.y + bf2f(e1.x >> 16)), pacc);
      pacc = fmaf(aw_r[10], tanhfast(hpc.z + bf2f(e1.y & 0xffffu)), pacc);
      pacc = fmaf(aw_r[11], tanhfast(hpc.w + bf2f(e1.y >> 16)), pacc);
      pacc = fmaf(aw_r[12], tanhfast(hpd.x + bf2f(e1.z & 0xffffu)), pacc);
      pacc = fmaf(aw_r[13], tanhfast(hpd.y + bf2f(e1.z >> 16)), pacc);
      pacc = fmaf(aw_r[14], tanhfast(hpd.z + bf2f(e1.w & 0xffffu)), pacc);
      pacc = fmaf(aw_r[15], tanhfast(hpd.w + bf2f(e1.w >> 16)), pacc);
      pacc += __shfl_down(pacc, 4, 8);
      pacc += __shfl_down(pacc, 2, 8);
      pacc += __shfl_down(pacc, 1, 8);
      if (ko8 == 0) scores[sidx] = pacc;
    }
    __syncthreads();
    // --- softmax over S (wave 0) ---
    if (tid < 64) {
      const float x = scores[tid];
      float m = x;
      #pragma unroll
      for (int d2 = 32; d2 >= 1; d2 >>= 1) m = fmaxf(m, __shfl_xor(m, d2, 64));
      const float e = __expf(x - m);
      float ssum = e;
      #pragma unroll
      for (int d2 = 32; d2 >= 1; d2 >>= 1) ssum += __shfl_xor(ssum, d2, 64);
      awlds[tid] = e / ssum;
    }
    __syncthreads();
    // --- ctx (4-way split over s); no trailing barrier needed ---
    {
      float cx = 0.0f;
      #pragma unroll
      for (int i = 0; i < 16; ++i) {
        const int s2 = kq*16 + i;
        cx = fmaf(awlds[s2], enc_b[s2*ENS + r], cx);
      }
      cx += __shfl_xor(cx, 1, 64);
      cx += __shfl_xor(cx, 2, 64);
      if (kq == 0) flat[(size_t)b*16384 + t*256 + 128 + r] = cx;
    }
  }
}

__global__ void k_head(const float* __restrict__ a4, const float* __restrict__ outW,
                       const float* __restrict__ outb, void* __restrict__ out,
                       const int* __restrict__ dflag)
{
  const int b = threadIdx.x;
  float acc = outb[0];
  #pragma unroll 8
  for (int k = 0; k < 128; ++k)
    acc = fmaf(outW[k], tanhfast(a4[b*128 + k]), acc);
  if (*dflag) ((u16*)out)[b] = f2bf(acc);
  else        ((float*)out)[b] = acc;
}

extern "C" void kernel_launch(void* const* d_in, const int* in_sizes, int n_in,
                              void* d_out, int out_size, void* d_ws, size_t ws_size,
                              hipStream_t stream)
{
  (void)in_sizes; (void)n_in; (void)out_size; (void)ws_size;

  float* p = (float*)d_ws;
  int*   flagp = (int*)p;    p += 64;
  float* x0    = p; p += 64*64*64;
  float* cl1Wih = p; p += 512*64;
  float* cl1Whh = p; p += 512*128;
  float* cl1b   = p; p += 512;
  float* c2fWih = p; p += 512*128;
  float* c2fWhh = p; p += 512*128;
  float* c2fb   = p; p += 512;
  float* c2bWih = p; p += 512*128;
  float* c2bWhh = p; p += 512*128;
  float* c2bb   = p; p += 512;
  float* c3fWih = p; p += 512*256;
  float* c3fWhh = p; p += 512*128;
  float* c3fb   = p; p += 512;
  float* c3bWih = p; p += 512*256;
  float* c3bWhh = p; p += 512*128;
  float* c3bb   = p; p += 512;
  float* ceWih  = p; p += 512*256;
  float* ceWhh  = p; p += 512*128;
  float* ceb    = p; p += 512;
  float* cdWih  = p; p += 512*128;
  float* cdWhh  = p; p += 512*128;
  float* cdb    = p; p += 512;
  float* cattW  = p; p += 128*128;
  float* cattw  = p; p += 128;
  float* cW1b   = p; p += 1024;
  float* cW2b   = p; p += 512;
  float* cW3b   = p; p += 256;
  float* cW4b   = p; p += 128;
  float* coW    = p; p += 128;
  float* cob    = p; p += 16;
  float* Zf   = p; p += 4096*512;
  float* Zb   = p; p += 4096*512;
  float* h1   = p; p += 4096*128;
  float* x2   = p; p += 4096*256;
  float* x3   = p; p += 4096*256;
  float* enco = p; p += 4096*128;
  float* encp = p; p += 4096*128;
  float* ec   = p; p += 64*128;
  float* flat = p; p += 64*16384;
  float* a1   = p; p += 64*1024;
  float* a2   = p; p += 64*512;
  float* a3   = p; p += 64*256;
  float* a4   = p; p += 64*128;

  k_detect<<<1, 256, 0, stream>>>((const u32*)d_in[2], flagp);

  Jobs J;
  int nj = 0;
  auto add = [&](const void* s, float* d, int n) { J.j[nj].s = s; J.j[nj].d = d; J.j[nj].n = n; ++nj; };
  add(d_in[0],  x0,     64*64*64);
  add(d_in[1],  cl1Wih, 512*64);
  add(d_in[2],  cl1Whh, 512*128);
  add(d_in[3],  cl1b,   512);
  add(d_in[4],  c2fWih, 512*128);
  add(d_in[5],  c2fWhh, 512*128);
  add(d_in[6],  c2fb,   512);
  add(d_in[7],  c2bWih, 512*128);
  add(d_in[8],  c2bWhh, 512*128);
  add(d_in[9],  c2bb,   512);
  add(d_in[10], c3fWih, 512*256);
  add(d_in[11], c3fWhh, 512*128);
  add(d_in[12], c3fb,   512);
  add(d_in[13], c3bWih, 512*256);
  add(d_in[14], c3bWhh, 512*128);
  add(d_in[15], c3bb,   512);
  add(d_in[16], ceWih,  512*256);
  add(d_in[17], ceWhh,  512*128);
  add(d_in[18], ceb,    512);
  add(d_in[19], cdWih,  512*128);
  add(d_in[20], cdWhh,  512*128);
  add(d_in[21], cdb,    512);
  add(d_in[22], cattW,  128*128);
  add(d_in[23], cattw,  128);
  add(d_in[25], cW1b,   1024);
  add(d_in[27], cW2b,   512);
  k_cvt_all<<<dim3(32, nj), 256, 0, stream>>>(J, flagp);

  Jobs J2;
  int nj2 = 0;
  auto add2 = [&](const void* s, float* d, int n) { J2.j[nj2].s = s; J2.j[nj2].d = d; J2.j[nj2].n = n; ++nj2; };
  add2(d_in[29], cW3b, 256);
  add2(d_in[31], cW4b, 128);
  add2(d_in[32], coW,  128);
  add2(d_in[33], cob,  1);
  k_cvt_all<<<dim3(4, nj2), 256, 0, stream>>>(J2, flagp);

  // lstm1
  k_gemm<<<dim3(64,8,1), 256, 0, stream>>>(x0, 64, cl1Wih, 64, cl1b, Zf, 512, 64, 0, 0, 0, flagp);
  k_rec<<<64, 512, 0, stream>>>(Zf, Zf, cl1Whh, cl1Whh, h1, 128, 0, 0, nullptr);

  // biLSTM 2
  k_gemm<<<dim3(64,8,1), 256, 0, stream>>>(h1, 128, c2fWih, 128, c2fb, Zf, 512, 128, 0, 0, 0, flagp);
  k_gemm<<<dim3(64,8,1), 256, 0, stream>>>(h1, 128, c2bWih, 128, c2bb, Zb, 512, 128, 0, 0, 0, flagp);
  k_rec<<<128, 512, 0, stream>>>(Zf, Zb, c2fWhh, c2bWhh, x2, 256, 0, 128, nullptr);

  // biLSTM 3
  k_gemm<<<dim3(64,8,1), 256, 0, stream>>>(x2, 256, c3fWih, 256, c3fb, Zf, 512, 256, 0, 0, 0, flagp);
  k_gemm<<<dim3(64,8,1), 256, 0, stream>>>(x2, 256, c3bWih, 256, c3bb, Zb, 512, 256, 0, 0, 0, flagp);
  k_rec<<<128, 512, 0, stream>>>(Zf, Zb, c3fWhh, c3bWhh, x3, 256, 0, 128, nullptr);

  // encoder
  k_gemm<<<dim3(64,8,1), 256, 0, stream>>>(x3, 256, ceWih, 256, ceb, Zf, 512, 256, 0, 0, 0, flagp);
  k_rec<<<64, 512, 0, stream>>>(Zf, Zf, ceWhh, ceWhh, enco, 128, 0, 0, ec);

  // hoisted attention projection of enc_out
  k_gemm<<<dim3(64,2,1), 256, 0, stream>>>(enco, 128, cattW, 128, nullptr, encp, 128, 128, 0, 0, 0, flagp);

  // decoder + attention -> flat [64, 16384]
  k_dec<<<64, 512, 0, stream>>>(enco, encp, ec, cdWih, cdWhh, cdb, cattW, cattw, flat);

  // MLP
  k_init<<<(64*1024+255)/256, 256, 0, stream>>>(cW1b, a1, 64*1024, 1023);
  k_gemm<<<dim3(1,16,16), 256, 0, stream>>>(flat, 16384, d_in[24], 16384, nullptr, a1, 1024, 16384, 0, 1, 1, flagp);
  k_init<<<(64*512+255)/256, 256, 0, stream>>>(cW2b, a2, 64*512, 511);
  k_gemm<<<dim3(1,8,4), 256, 0, stream>>>(a1, 1024, d_in[26], 1024, nullptr, a2, 512, 1024, 1, 1, 1, flagp);
  k_init<<<(64*256+255)/256, 256, 0, stream>>>(cW3b, a3, 64*256, 255);
  k_gemm<<<dim3(1,4,4), 256, 0, stream>>>(a2, 512, d_in[28], 512, nullptr, a3, 256, 512, 1, 1, 1, flagp);
  k_init<<<(64*128+255)/256, 256, 0, stream>>>(cW4b, a4, 64*128, 127);
  k_gemm<<<dim3(1,2,2), 256, 0, stream>>>(a3, 256, d_in[30], 256, nullptr, a4, 128, 256, 1, 1, 1, flagp);

  k_head<<<1, 64, 0, stream>>>(a4, coW, cob, d_out, flagp);
}